// Round 4
// baseline (754.117 us; speedup 1.0000x reference)
//
#include <hip/hip_runtime.h>

// SNN residual block, fully fused, round 4:
//  r2: uniform-LDS w reads -> DS pipe bound (305us).
//  r3: w via readfirstlane/s_load -> SMEM+lgkmcnt serialization, 27% VALUBusy (272us).
//  r4: w via VMEM broadcast loads (same addr across lanes, L1-hot, vmcnt-pipelined).
//      Math bitwise-identical to r3 (absmax must stay 0.001953125).
// Shapes: x[4][32][512][1024], w1[64][512], w2[32][64], out[4][4][32][8][1024].

#define T_   4
#define B_   32
#define C_   512
#define NPIX 1024
#define HID  64
#define OUTC 32
#define NT   64            // n-columns per block
#define CK   32            // c-rows per staged chunk
#define NCH  (C_ / CK)     // 16 chunks

typedef const __attribute__((address_space(1))) void* gas_t;
typedef __attribute__((address_space(3))) void* las_t;
typedef float v2f __attribute__((ext_vector_type(2)));

// Force a pointer into VGPRs so uniformity analysis can't scalarize its loads.
__device__ inline const float* launder_vgpr(const float* p) {
    asm("" : "+v"(p));
    return p;
}

__global__ void w2_transpose(const float* __restrict__ w2, float* __restrict__ wst)
{
    const int o = threadIdx.x;           // 0..63
    #pragma unroll
    for (int p = 0; p < OUTC; ++p)
        wst[o * OUTC + p] = w2[p * HID + o];
}

__global__ __launch_bounds__(256, 2)
void snn_fused(const float* __restrict__ x,  const float* __restrict__ w1,
               const float* __restrict__ g1, const float* __restrict__ b1,
               const float* __restrict__ m1, const float* __restrict__ v1,
               const float* __restrict__ wst,   // transposed w2 [o][p], in d_ws
               const float* __restrict__ g2, const float* __restrict__ b2,
               const float* __restrict__ m2, const float* __restrict__ v2,
               float* __restrict__ out)
{
    __shared__ float xs[2][T_][CK][NT];          // 64 KB, double-buffered x tile [t][c][n]
    __shared__ unsigned short spk[T_][4][NT];    //  2 KB, spike masks per (t, o-group, n)
    __shared__ float s2s[OUTC], sh2s[OUTC];

    const int tid = threadIdx.x;
    const int wv  = tid >> 6;        // wave id (divergent to the compiler -> VMEM w loads)
    const int ln  = tid & 63;        // lane = n within tile
    const int b   = blockIdx.y;
    const int n0  = blockIdx.x * NT;

    // ---- one-time: BN2 fold ----
    if (tid < OUTC) {
        float sc  = g2[tid] / sqrtf(v2[tid] + 1e-5f);
        s2s[tid]  = sc;
        sh2s[tid] = b2[tid] - m2[tid] * sc;
    }

    // ---- async staging: chunk ch of x into buffer bf (wave wv loads t=wv) ----
    #define STAGE(ch, bf) do {                                                          \
        const int c0_ = (ch) * CK;                                                      \
        const float* gx_ = x + (((size_t)wv * B_ + b) * C_ + c0_) * NPIX + n0;          \
        _Pragma("unroll")                                                               \
        for (int j_ = 0; j_ < 8; ++j_) {                                                \
            const float* src_ = gx_ + (j_ * 4 + (ln >> 4)) * NPIX + ((ln & 15) << 2);   \
            __builtin_amdgcn_global_load_lds((gas_t)src_, (las_t)&xs[bf][wv][j_ * 4][0], 16, 0, 0); \
        }                                                                               \
    } while (0)

    // ---- phase 1: GEMM1; packed accumulators h01=(t0,t1), h23=(t2,t3) per o' ----
    v2f h01[16], h23[16];
    #pragma unroll
    for (int i = 0; i < 16; ++i) { h01[i] = (v2f){0.f, 0.f}; h23[i] = (v2f){0.f, 0.f}; }

    // w1 row base: wv-derived (divergent to compiler) -> global_load, same addr
    // across lanes -> single L1 broadcast fetch per instr, vmcnt-pipelined.
    const float* w1v = w1 + (size_t)wv * 16 * C_;

    STAGE(0, 0);
    __syncthreads();   // chunk 0 resident

    int bf = 0;
    for (int ch = 0; ch < NCH; ++ch) {
        if (ch + 1 < NCH) STAGE(ch + 1, bf ^ 1);   // async prefetch next chunk
        const float* wc = w1v + ch * CK;
        #pragma unroll
        for (int c4 = 0; c4 < CK; c4 += 4) {
            v2f x01[4], x23[4];
            #pragma unroll
            for (int cc = 0; cc < 4; ++cc) {       // lane-contiguous b32, conflict-free
                x01[cc] = (v2f){ xs[bf][0][c4 + cc][ln], xs[bf][1][c4 + cc][ln] };
                x23[cc] = (v2f){ xs[bf][2][c4 + cc][ln], xs[bf][3][c4 + cc][ln] };
            }
            #pragma unroll
            for (int i = 0; i < 16; ++i) {
                const float4 wq = *(const float4*)(wc + i * C_ + c4);   // VMEM broadcast
                const float wa[4] = {wq.x, wq.y, wq.z, wq.w};
                #pragma unroll
                for (int cc = 0; cc < 4; ++cc) {
                    const v2f ws = { wa[cc], wa[cc] };
                    h01[i] = __builtin_elementwise_fma(x01[cc], ws, h01[i]);
                    h23[i] = __builtin_elementwise_fma(x23[cc], ws, h23[i]);
                }
            }
        }
        __syncthreads();   // chunk ch+1 staged; all reads of bf done before overwrite
        bf ^= 1;
    }

    // ---- BN1 fold + LIF recurrence (4 t in registers), pack spike bits ----
    {
        unsigned int msk[T_] = {0u, 0u, 0u, 0u};
        #pragma unroll
        for (int i = 0; i < 16; ++i) {
            const int o = wv * 16 + i;
            const float sc = g1[o] / sqrtf(v1[o] + 1e-5f);
            const float sh = b1[o] - m1[o] * sc;
            const float hh[T_] = { h01[i].x, h01[i].y, h23[i].x, h23[i].y };
            float v = 0.f;
            #pragma unroll
            for (int t = 0; t < T_; ++t) {
                const float hb = hh[t] * sc + sh;
                v = v + (hb - v) * 0.5f;                     // v += (x - v)/tau, tau = 2
                const bool sp = (v >= 1.0f);
                if (sp) msk[t] |= (1u << i);
                v = sp ? 0.f : v;                            // hard reset
            }
        }
        #pragma unroll
        for (int t = 0; t < T_; ++t)
            spk[t][wv][ln] = (unsigned short)msk[t];
    }
    __syncthreads();

    // ---- phase 2: spike-GEMM2 (wave = t) via VMEM-broadcast w2t, BN2, store ----
    {
        const int t = wv;
        const unsigned int mlo = (unsigned int)spk[t][0][ln] | ((unsigned int)spk[t][1][ln] << 16);
        const unsigned int mhi = (unsigned int)spk[t][2][ln] | ((unsigned int)spk[t][3][ln] << 16);

        const float* wstv = launder_vgpr(wst);   // kill uniformity -> VMEM loads

        v2f y2[16];
        #pragma unroll
        for (int p2 = 0; p2 < 16; ++p2) y2[p2] = (v2f){0.f, 0.f};

        #pragma unroll 8
        for (int o = 0; o < 32; ++o) {
            const float sp = (float)((mlo >> o) & 1u);
            const v2f spv = { sp, sp };
            const float* wr = wstv + o * OUTC;
            #pragma unroll
            for (int q = 0; q < 4; ++q) {
                const float4 wq = *(const float4*)(wr + q * 4);      // VMEM broadcast
                y2[q * 2 + 0] = __builtin_elementwise_fma(spv, (v2f){wq.x, wq.y}, y2[q * 2 + 0]);
                y2[q * 2 + 1] = __builtin_elementwise_fma(spv, (v2f){wq.z, wq.w}, y2[q * 2 + 1]);
            }
            #pragma unroll
            for (int q = 0; q < 4; ++q) {
                const float4 wq = *(const float4*)(wr + 16 + q * 4);
                y2[8 + q * 2 + 0] = __builtin_elementwise_fma(spv, (v2f){wq.x, wq.y}, y2[8 + q * 2 + 0]);
                y2[8 + q * 2 + 1] = __builtin_elementwise_fma(spv, (v2f){wq.z, wq.w}, y2[8 + q * 2 + 1]);
            }
        }
        #pragma unroll 8
        for (int o = 0; o < 32; ++o) {
            const float sp = (float)((mhi >> o) & 1u);
            const v2f spv = { sp, sp };
            const float* wr = wstv + (o + 32) * OUTC;
            #pragma unroll
            for (int q = 0; q < 4; ++q) {
                const float4 wq = *(const float4*)(wr + q * 4);
                y2[q * 2 + 0] = __builtin_elementwise_fma(spv, (v2f){wq.x, wq.y}, y2[q * 2 + 0]);
                y2[q * 2 + 1] = __builtin_elementwise_fma(spv, (v2f){wq.z, wq.w}, y2[q * 2 + 1]);
            }
            #pragma unroll
            for (int q = 0; q < 4; ++q) {
                const float4 wq = *(const float4*)(wr + 16 + q * 4);
                y2[8 + q * 2 + 0] = __builtin_elementwise_fma(spv, (v2f){wq.x, wq.y}, y2[8 + q * 2 + 0]);
                y2[8 + q * 2 + 1] = __builtin_elementwise_fma(spv, (v2f){wq.z, wq.w}, y2[8 + q * 2 + 1]);
            }
        }

        // out[cg][t][b][l][n], p = cg*8 + l
        #pragma unroll
        for (int p2 = 0; p2 < 16; ++p2) {
            const float yy[2] = { y2[p2].x, y2[p2].y };
            #pragma unroll
            for (int k = 0; k < 2; ++k) {
                const int p  = p2 * 2 + k;
                const int cg = p >> 3, l = p & 7;
                const size_t idx = ((size_t)(((cg * T_ + t) * B_ + b) * 8 + l) << 10) + n0 + ln;
                out[idx] = yy[k] * s2s[p] + sh2s[p];
            }
        }
    }
    #undef STAGE
}

extern "C" void kernel_launch(void* const* d_in, const int* in_sizes, int n_in,
                              void* d_out, int out_size, void* d_ws, size_t ws_size,
                              hipStream_t stream)
{
    const float* x  = (const float*)d_in[0];
    const float* w1 = (const float*)d_in[1];
    const float* g1 = (const float*)d_in[2];
    const float* b1 = (const float*)d_in[3];
    const float* m1 = (const float*)d_in[4];
    const float* v1 = (const float*)d_in[5];
    const float* w2 = (const float*)d_in[6];
    const float* g2 = (const float*)d_in[7];
    const float* b2 = (const float*)d_in[8];
    const float* m2 = (const float*)d_in[9];
    const float* v2 = (const float*)d_in[10];

    float* wst = (float*)d_ws;                       // 64x32 transposed w2

    w2_transpose<<<1, 64, 0, stream>>>(w2, wst);
    dim3 grid(NPIX / NT, B_);                        // 16 x 32 = 512 blocks, 2 per CU
    snn_fused<<<grid, 256, 0, stream>>>(x, w1, g1, b1, m1, v1, wst, g2, b2, m2, v2,
                                        (float*)d_out);
}

// Round 5
// 584.233 us; speedup vs baseline: 1.2908x; 1.2908x over previous
//
#include <hip/hip_runtime.h>

// SNN residual block, fully fused, round 5: wave-per-timestep restructure.
//  r2: uniform-LDS w -> DS-pipe bound (305us). r3: s_load w + 4x x re-read +
//  barriers -> lgkm drains (272us). r4: VMEM-broadcast w -> vmcnt collision
//  with global_load_lds staging (482us).
//  r5: wave=t. x read ONCE per block (own-region staging, NO barriers in GEMM
//  loop, per-wave vmcnt handshake). w1 pre-transposed [c][o] -> uniform
//  s_load rows on lgkm; h re-shuffled through dead x-buffers for LIF.
//  Math bitwise-identical to r3 (absmax canary: 0.001953125).
// Shapes: x[4][32][512][1024], w1[64][512], w2[32][64], out[4][4][32][8][1024].

#define T_   4
#define B_   32
#define C_   512
#define NPIX 1024
#define HID  64
#define OUTC 32
#define NT   64            // n-columns per block
#define CK   32            // c-rows per staged chunk
#define NCH  (C_ / CK)     // 16 chunks

typedef const __attribute__((address_space(1))) void* gas_t;
typedef __attribute__((address_space(3))) void* las_t;
typedef float v2f __attribute__((ext_vector_type(2)));

// Pre-transpose: w1t[c][o] = w1[o][c]; w2t[o][p] = w2[p][o]. Runs once, ~us.
__global__ void w_prep(const float* __restrict__ w1, const float* __restrict__ w2,
                       float* __restrict__ w1t, float* __restrict__ w2t)
{
    const int idx = blockIdx.x * 256 + threadIdx.x;   // 0..32767
    const int c = idx >> 6, o = idx & 63;
    w1t[idx] = w1[o * C_ + c];
    if (idx < HID * OUTC) {                           // 2048
        const int oo = idx >> 5, p = idx & 31;
        w2t[idx] = w2[p * HID + oo];
    }
}

__global__ __launch_bounds__(256, 2)
void snn_fused(const float* __restrict__ x,  const float* __restrict__ w1t,
               const float* __restrict__ g1, const float* __restrict__ b1,
               const float* __restrict__ m1, const float* __restrict__ v1,
               const float* __restrict__ w2t,
               const float* __restrict__ g2, const float* __restrict__ b2,
               const float* __restrict__ m2, const float* __restrict__ v2,
               float* __restrict__ out)
{
    // 64 KB pool: phase 1 = xs[bf][wave][c][n] (wave-private regions);
    // after GEMM reused for the h-exchange (each wave writes its OWN regions).
    __shared__ float pool[2 * T_ * CK * NT];
    __shared__ unsigned short spk[T_][4][NT];    // 2 KB spike masks
    __shared__ float s2s[OUTC], sh2s[OUTC];

    const int tid = threadIdx.x;
    const int wv  = tid >> 6;        // wave id == timestep t (phases 1 & 2)
    const int ln  = tid & 63;        // lane = n within tile
    const int b   = blockIdx.y;
    const int n0  = blockIdx.x * NT;

    if (tid < OUTC) {                // BN2 fold
        float sc  = g2[tid] / sqrtf(v2[tid] + 1e-5f);
        s2s[tid]  = sc;
        sh2s[tid] = b2[tid] - m2[tid] * sc;
    }

    float* xw0 = pool + (0 * T_ + wv) * CK * NT;   // this wave's buffer 0
    float* xw1 = pool + (1 * T_ + wv) * CK * NT;   // this wave's buffer 1

    // Stage chunk ch of x[t=wv][b][c0..c0+31][n0..n0+63] into dst (8 x 1KB).
    #define STAGE(ch, dst) do {                                                         \
        const int c0_ = (ch) * CK;                                                      \
        const float* gx_ = x + ((size_t)(wv * B_ + b) * C_ + c0_) * NPIX + n0;          \
        _Pragma("unroll")                                                               \
        for (int j_ = 0; j_ < 8; ++j_) {                                                \
            const float* src_ = gx_ + (j_ * 4 + (ln >> 4)) * NPIX + ((ln & 15) << 2);   \
            __builtin_amdgcn_global_load_lds((gas_t)src_, (las_t)((dst) + j_ * 4 * NT), 16, 0, 0); \
        }                                                                               \
    } while (0)

    // ---- phase 1: GEMM1. acc2[q] = h[t=wv][o=(2q,2q+1)][n=ln] ----
    v2f acc2[32];
    #pragma unroll
    for (int q = 0; q < 32; ++q) acc2[q] = (v2f){0.f, 0.f};

    STAGE(0, xw0);
    asm volatile("s_waitcnt vmcnt(0)" ::: "memory");   // own chunk 0 resident

    float* xwc = xw0;    // compute buffer
    float* xwn = xw1;    // staging buffer
    for (int ch = 0; ch < NCH; ++ch) {
        if (ch + 1 < NCH) STAGE(ch + 1, xwn);          // async, own region, no barrier
        const float* wc = w1t + (size_t)(ch * CK) * HID;   // uniform -> s_load rows
        float xv[CK];
        #pragma unroll
        for (int c = 0; c < CK; ++c) xv[c] = xwc[c * NT + ln];   // own t only
        #pragma unroll
        for (int c = 0; c < CK; ++c) {
            const float* wr = wc + c * HID;            // w1t row: 64 contiguous floats
            const v2f xsp = { xv[c], xv[c] };
            #pragma unroll
            for (int q = 0; q < 16; ++q) {
                const float4 wq = *(const float4*)(wr + q * 4);   // uniform -> SGPR
                acc2[q * 2 + 0] = __builtin_elementwise_fma(xsp, (v2f){wq.x, wq.y}, acc2[q * 2 + 0]);
                acc2[q * 2 + 1] = __builtin_elementwise_fma(xsp, (v2f){wq.z, wq.w}, acc2[q * 2 + 1]);
            }
        }
        asm volatile("s_waitcnt vmcnt(0)" ::: "memory");   // next chunk resident
        float* tmp = xwc; xwc = xwn; xwn = tmp;
    }

    // ---- h-exchange through the (dead) x buffers: wave wv writes ONLY its own
    // two regions (o<32 -> buffer0 region, o>=32 -> buffer1 region). One barrier.
    #pragma unroll
    for (int q = 0; q < 16; ++q) {
        xw0[(2 * q + 0) * NT + ln] = acc2[q].x;        // o = 2q
        xw0[(2 * q + 1) * NT + ln] = acc2[q].y;        // o = 2q+1
        xw1[(2 * q + 0) * NT + ln] = acc2[16 + q].x;   // o = 32+2q
        xw1[(2 * q + 1) * NT + ln] = acc2[16 + q].y;   // o = 32+2q+1
    }
    __syncthreads();

    // ---- LIF: wave wv now owns o-group wv (16 o's), gathers h over all t ----
    {
        float hr[16][T_];
        #pragma unroll
        for (int i = 0; i < 16; ++i) {
            const int o = wv * 16 + i;
            #pragma unroll
            for (int t = 0; t < T_; ++t)
                hr[i][t] = pool[(((o >> 5) * T_ + t) * CK + (o & 31)) * NT + ln];
        }
        unsigned int msk[T_] = {0u, 0u, 0u, 0u};
        #pragma unroll
        for (int i = 0; i < 16; ++i) {
            const int o = wv * 16 + i;
            const float sc = g1[o] / sqrtf(v1[o] + 1e-5f);
            const float sh = b1[o] - m1[o] * sc;
            float v = 0.f;
            #pragma unroll
            for (int t = 0; t < T_; ++t) {
                const float hb = hr[i][t] * sc + sh;
                v = v + (hb - v) * 0.5f;                     // v += (x - v)/tau, tau = 2
                const bool sp = (v >= 1.0f);
                if (sp) msk[t] |= (1u << i);
                v = sp ? 0.f : v;                            // hard reset
            }
        }
        #pragma unroll
        for (int t = 0; t < T_; ++t)
            spk[t][wv][ln] = (unsigned short)msk[t];
    }
    __syncthreads();

    // ---- phase 2: spike-GEMM2 (wave = t), scalar w2t rows, BN2, store ----
    {
        const int t = wv;
        const unsigned int mlo = (unsigned int)spk[t][0][ln] | ((unsigned int)spk[t][1][ln] << 16);
        const unsigned int mhi = (unsigned int)spk[t][2][ln] | ((unsigned int)spk[t][3][ln] << 16);

        v2f y2[16];
        #pragma unroll
        for (int p2 = 0; p2 < 16; ++p2) y2[p2] = (v2f){0.f, 0.f};

        #pragma unroll 8
        for (int o = 0; o < 32; ++o) {
            const float sp = (float)((mlo >> o) & 1u);
            const v2f spv = { sp, sp };
            const float* wr = w2t + o * OUTC;            // uniform -> s_load
            #pragma unroll
            for (int p2 = 0; p2 < 16; ++p2)
                y2[p2] = __builtin_elementwise_fma(spv, ((const v2f*)wr)[p2], y2[p2]);
        }
        #pragma unroll 8
        for (int o = 0; o < 32; ++o) {
            const float sp = (float)((mhi >> o) & 1u);
            const v2f spv = { sp, sp };
            const float* wr = w2t + (o + 32) * OUTC;     // uniform -> s_load
            #pragma unroll
            for (int p2 = 0; p2 < 16; ++p2)
                y2[p2] = __builtin_elementwise_fma(spv, ((const v2f*)wr)[p2], y2[p2]);
        }

        // out[cg][t][b][l][n], p = cg*8 + l
        #pragma unroll
        for (int p2 = 0; p2 < 16; ++p2) {
            const float yy[2] = { y2[p2].x, y2[p2].y };
            #pragma unroll
            for (int k = 0; k < 2; ++k) {
                const int p  = p2 * 2 + k;
                const int cg = p >> 3, l = p & 7;
                const size_t idx = ((size_t)(((cg * T_ + t) * B_ + b) * 8 + l) << 10) + n0 + ln;
                out[idx] = yy[k] * s2s[p] + sh2s[p];
            }
        }
    }
    #undef STAGE
}

extern "C" void kernel_launch(void* const* d_in, const int* in_sizes, int n_in,
                              void* d_out, int out_size, void* d_ws, size_t ws_size,
                              hipStream_t stream)
{
    const float* x  = (const float*)d_in[0];
    const float* w1 = (const float*)d_in[1];
    const float* g1 = (const float*)d_in[2];
    const float* b1 = (const float*)d_in[3];
    const float* m1 = (const float*)d_in[4];
    const float* v1 = (const float*)d_in[5];
    const float* w2 = (const float*)d_in[6];
    const float* g2 = (const float*)d_in[7];
    const float* b2 = (const float*)d_in[8];
    const float* m2 = (const float*)d_in[9];
    const float* v2 = (const float*)d_in[10];

    float* w1t = (float*)d_ws;                       // 512x64  (128 KB)
    float* w2t = w1t + C_ * HID;                     // 64x32   (8 KB)

    w_prep<<<128, 256, 0, stream>>>(w1, w2, w1t, w2t);
    dim3 grid(NPIX / NT, B_);                        // 16 x 32 = 512 blocks, 2/CU
    snn_fused<<<grid, 256, 0, stream>>>(x, w1t, g1, b1, m1, v1, w2t, g2, b2, m2, v2,
                                        (float*)d_out);
}